// Round 10
// baseline (229.512 us; speedup 1.0000x reference)
//
#include <hip/hip_runtime.h>
#include <math.h>

#define DIM_ 512
#define HID_ 2048
#define B_ 8
#define N_ 1024
#define ROWS_ 8192   // B_*N_
#define TOPK 16      // exact: gate at rank>=16 is <= e^-54 (k<12), contribution ~1e-20

typedef __attribute__((ext_vector_type(8))) short short8;
typedef __attribute__((ext_vector_type(16))) float float16v;

__device__ __forceinline__ float sigm(float x) { return 1.f / (1.f + __expf(-x)); }

__device__ __forceinline__ short f2bf(float f) {           // RNE fp32 -> bf16
    unsigned u = __float_as_uint(f);
    u += 0x7FFF + ((u >> 16) & 1);
    return (short)(u >> 16);
}

__device__ __forceinline__ float bf2f(unsigned short s) {
    return __uint_as_float((unsigned)s << 16);
}

__device__ __forceinline__ unsigned f2ord(float f) {       // monotone fp32 -> u32
    unsigned u = __float_as_uint(f);
    return (u & 0x80000000u) ? ~u : (u | 0x80000000u);
}

__device__ __forceinline__ void gload16(const short* g, short* l) {
    __builtin_amdgcn_global_load_lds(
        (const __attribute__((address_space(1))) void*)g,
        (__attribute__((address_space(3))) void*)l, 16, 0, 0);
}

// ---------------- fused prep: pooled partials + x->bf16  |  weights->bf16 ----------------
__global__ __launch_bounds__(512)
void prep_kernel(const float* __restrict__ x, float* __restrict__ part, short* __restrict__ xb,
                 const float* __restrict__ w1, const float* __restrict__ w2,
                 short* __restrict__ o1, short* __restrict__ o2) {
    const int bx = blockIdx.x;
    if (bx < 256) {
        const int b = bx >> 5, chunk = bx & 31;
        const int c = threadIdx.x;                     // 512
        const long long base = ((long long)b * N_ + chunk * 32) * DIM_ + c;
        const float* xp = x + base;
        short* xo = xb + base;
        float s = 0.f;
        for (int n = 0; n < 32; ++n) {
            const float v = xp[(long long)n * DIM_];
            s += v;
            xo[(long long)n * DIM_] = f2bf(v);
        }
        part[(long long)bx * DIM_ + c] = s;
    } else {
        const int n4 = HID_ * DIM_ / 4;                // 262144 float4 per matrix
        int i = (bx - 256) * 2048 + threadIdx.x;
#pragma unroll
        for (int t = 0; t < 4; ++t, i += 512) {
            const float* in = (i < n4) ? w1 : w2;
            short* out = (i < n4) ? o1 : o2;
            const int j = (i < n4) ? i : (i - n4);
            const float4 v = *(const float4*)(in + (long long)j * 4);
            short4 o;
            o.x = f2bf(v.x); o.y = f2bf(v.y); o.z = f2bf(v.z); o.w = f2bf(v.w);
            *(short4*)(out + (long long)j * 4) = o;
        }
    }
}

// ---------------- pooled reduce + head nets (fused): k_cont (B,3), w (B,3) ----------------
__global__ __launch_bounds__(512)
void pool_heads_kernel(const float* __restrict__ part,
                       const float* __restrict__ k1w, const float* __restrict__ k1b,
                       const float* __restrict__ k2w, const float* __restrict__ k2b,
                       const float* __restrict__ w1w, const float* __restrict__ w1b,
                       const float* __restrict__ w2w, const float* __restrict__ w2b,
                       float* __restrict__ kcont, float* __restrict__ wbr) {
    const int b = blockIdx.x;
    const int t = threadIdx.x;                     // 512
    __shared__ float sp[DIM_];
    __shared__ float kh[128], wh[128];
    __shared__ float wraw[4];
    float s = 0.f;
    for (int g = 0; g < 32; ++g) s += part[((long long)b * 32 + g) * DIM_ + t];
    sp[t] = s * (1.f / 1024.f);
    __syncthreads();
    if (t < 128) {
        float ak = k1b[t], aw = w1b[t];
        for (int k = 0; k < DIM_; ++k) {
            const float pv = sp[k];
            ak = fmaf(pv, k1w[t * DIM_ + k], ak);
            aw = fmaf(pv, w1w[t * DIM_ + k], aw);
        }
        kh[t] = fmaxf(ak, 0.f);
        wh[t] = fmaxf(aw, 0.f);
    }
    __syncthreads();
    if (t < 3) {
        float rk = k2b[t], rw = w2b[t];
        for (int k = 0; k < 128; ++k) {
            rk = fmaf(kh[k], k2w[t * 128 + k], rk);
            rw = fmaf(wh[k], w2w[t * 128 + k], rw);
        }
        kcont[b * 3 + t] = 1.f + 11.f * sigm(rk);
        wraw[t] = rw;
    }
    __syncthreads();
    if (t == 0) {
        const float m = fmaxf(wraw[0], fmaxf(wraw[1], wraw[2]));
        const float e0 = __expf(wraw[0] - m), e1 = __expf(wraw[1] - m), e2 = __expf(wraw[2] - m);
        const float inv = 1.f / (e0 + e1 + e2);
        wbr[b * 3 + 0] = e0 * inv;
        wbr[b * 3 + 1] = e1 * inv;
        wbr[b * 3 + 2] = e2 * inv;
    }
}

// ---------------- bf16 MFMA NT GEMM, 32x32x16, 128xBN tile ----------------
// BN=128: 4 waves as 2x2, each 64x64 = 2x2 frags.  BN=64: 4 waves as 2x2,
// each 64x32 = 2x1 frags (direct fc2, 512 blocks without split-K).
// Wave n-offset nl = (wv>>1)*(BN/2)  [R9 bug was BN/4 — overlapped+uncovered n].
// A/B frag: m|n = lane&31, k = (lane>>5)*8 + j.  C/D: col=lane&31,
// row=(reg&3)+8*(reg>>2)+4*(lane>>5)  [m74/m101-verified].
// OUTMODE: 0 = bf16 out, bias+relu; 1 = bf16 out, bias; 2 = fp32 raw (no bias)
template<int OUTMODE, int BN>
__global__ __launch_bounds__(256)
void gemm_mfma(const short* __restrict__ A, const short* __restrict__ Bm,
               const float* __restrict__ bias,
               float* __restrict__ outF, short* __restrict__ outB,
               int M, int N, int K, int lda, int ldb,
               long long sA, long long sB, long long sC) {
    constexpr int NJ = BN / 64;             // j-frags per wave (2 or 1)
    const int bz = blockIdx.z;
    A  += (long long)bz * sA;
    Bm += (long long)bz * sB;

    __shared__ short As[128 * 64];
    __shared__ short Bs[BN * 64];

    const int tid = threadIdx.x;
    const int lane = tid & 63;
    const int wv = tid >> 6;                // 0..3
    const int m0 = blockIdx.y * 128;
    const int n0 = blockIdx.x * BN;

    const int lrow = lane >> 3;             // 0..7
    const int cg = (lane & 7) ^ lrow;       // XOR swizzle

    const int ml = (wv & 1) * 64;
    const int nl = (wv >> 1) * (BN / 2);    // BN=128 -> 64, BN=64 -> 32
    const int fr = lane & 31;               // fragment row/col (m or n)
    const int khh = lane >> 5;              // k-half 0..1

    float16v acc[2][NJ];
#pragma unroll
    for (int i = 0; i < 2; ++i)
#pragma unroll
        for (int j = 0; j < NJ; ++j)
#pragma unroll
            for (int r = 0; r < 16; ++r) acc[i][j][r] = 0.f;

    for (int k0 = 0; k0 < K; k0 += 64) {
        __syncthreads();
#pragma unroll
        for (int i = 0; i < 4; ++i) {
            const int rloc = wv * 32 + i * 8 + lrow;
            gload16(A + (long long)(m0 + rloc) * lda + (k0 + cg * 8),
                    &As[(wv * 32 + i * 8) * 64]);
        }
#pragma unroll
        for (int i = 0; i < BN / 32; ++i) {
            const int rloc = wv * (BN / 4) + i * 8 + lrow;
            gload16(Bm + (long long)(n0 + rloc) * ldb + (k0 + cg * 8),
                    &Bs[(wv * (BN / 4) + i * 8) * 64]);
        }
        __syncthreads();
#pragma unroll
        for (int c = 0; c < 4; ++c) {           // 4 ksteps of K=16
            const int ch = c * 2 + khh;         // 8-elem chunk index
            short8 af[2], bfr[NJ];
#pragma unroll
            for (int i = 0; i < 2; ++i) {
                const int m = ml + i * 32 + fr;
                af[i] = *(const short8*)&As[m * 64 + ((ch ^ (m & 7)) * 8)];
            }
#pragma unroll
            for (int j = 0; j < NJ; ++j) {
                const int n = nl + j * 32 + fr;
                bfr[j] = *(const short8*)&Bs[n * 64 + ((ch ^ (n & 7)) * 8)];
            }
#pragma unroll
            for (int i = 0; i < 2; ++i)
#pragma unroll
                for (int j = 0; j < NJ; ++j)
                    acc[i][j] = __builtin_amdgcn_mfma_f32_32x32x16_bf16(
                        af[i], bfr[j], acc[i][j], 0, 0, 0);
        }
    }

    const long long outOfs = (long long)bz * sC;
#pragma unroll
    for (int i = 0; i < 2; ++i) {
#pragma unroll
        for (int j = 0; j < NJ; ++j) {
            const int ng = n0 + nl + j * 32 + fr;
            float bv = 0.f;
            if (OUTMODE != 2) bv = bias[ng];
#pragma unroll
            for (int r = 0; r < 16; ++r) {
                const int mg = m0 + ml + i * 32 + (r & 3) + 8 * (r >> 2) + 4 * khh;
                float v = acc[i][j][r] + bv;
                if (OUTMODE == 0) v = fmaxf(v, 0.f);
                const long long idx = outOfs + (long long)mg * N + ng;
                if (OUTMODE == 2) outF[idx] = v;
                else              outB[idx] = f2bf(v);
            }
        }
    }
}

// ---------------- fused per-row top-16 + aggregate (two-phase exact) ----------------
__global__ __launch_bounds__(256)
void topk_agg_kernel(const float* __restrict__ sim,
                     const float* __restrict__ kcont, const float* __restrict__ wbr,
                     const unsigned short* __restrict__ h, float* __restrict__ y) {
    const int wv = threadIdx.x >> 6;
    const int lane = threadIdx.x & 63;
    const int ll = lane & 15;
    const int row = blockIdx.x * 4 + wv;          // 2048 blocks * 4 waves
    const int b = row >> 10;
    const float* srow = sim + (long long)row * N_;

    float f[16];
    const int base = lane * 16;
#pragma unroll
    for (int q = 0; q < 4; ++q) {
        const float4 v = *(const float4*)(srow + base + q * 4);
        f[q * 4 + 0] = v.x; f[q * 4 + 1] = v.y; f[q * 4 + 2] = v.z; f[q * 4 + 3] = v.w;
    }

    // row max
    float lmax = f[0];
#pragma unroll
    for (int j = 1; j < 16; ++j) lmax = fmaxf(lmax, f[j]);
#pragma unroll
    for (int d = 32; d > 0; d >>= 1) lmax = fmaxf(lmax, __shfl_xor(lmax, d));
    const float maxv = lmax;

    // softmax denominator (full row, exact fp32)
    float lsum = 0.f;
#pragma unroll
    for (int j = 0; j < 16; ++j) lsum += __expf(f[j] - maxv);
#pragma unroll
    for (int d = 32; d > 0; d >>= 1) lsum += __shfl_xor(lsum, d);
    const float invden = 1.f / lsum;

    // ---- Phase A: u32 keys ----
    unsigned key[16];
#pragma unroll
    for (int j = 0; j < 16; ++j)
        key[j] = (f2ord(f[j]) & 0xFFFFFC00u) | (unsigned)(1023 - (base + j));

#pragma unroll
    for (int k = 2; k <= 16; k <<= 1) {
#pragma unroll
        for (int j = k >> 1; j > 0; j >>= 1) {
#pragma unroll
            for (int i = 0; i < 16; ++i) {
                const int l = i ^ j;
                if (l > i) {
                    const bool desc = ((i & k) == 0);
                    const unsigned a = key[i], bk = key[l];
                    const unsigned hi = (a > bk) ? a : bk;
                    const unsigned lo = (a > bk) ? bk : a;
                    key[i] = desc ? hi : lo;
                    key[l] = desc ? lo : hi;
                }
            }
        }
    }

#pragma unroll
    for (int d = 1; d < 64; d <<= 1) {
        unsigned other[16];
#pragma unroll
        for (int i = 0; i < 16; ++i)
            other[i] = __shfl_xor(key[15 - i], d);
#pragma unroll
        for (int i = 0; i < 16; ++i)
            key[i] = (key[i] > other[i]) ? key[i] : other[i];
#pragma unroll
        for (int j = 8; j > 0; j >>= 1) {
#pragma unroll
            for (int i = 0; i < 16; ++i) {
                if ((i & j) == 0) {
                    const unsigned a = key[i], bk = key[i | j];
                    key[i]     = (a > bk) ? a : bk;
                    key[i | j] = (a > bk) ? bk : a;
                }
            }
        }
    }

    // ---- Phase B: exact order of the 16 survivors ----
    unsigned k32 = key[0];
#pragma unroll
    for (int j = 1; j < 16; ++j) k32 = (ll == j) ? key[j] : k32;
    const int myidx = 1023 - (int)(k32 & 1023u);
    const float myval = srow[myidx];

    unsigned long long kx = ((unsigned long long)f2ord(myval) << 32)
                          | (unsigned)(1023 - myidx);
#pragma unroll
    for (int k = 2; k <= 16; k <<= 1) {
#pragma unroll
        for (int d = k >> 1; d > 0; d >>= 1) {
            const unsigned long long other = __shfl_xor(kx, d);
            const bool keepMax = (((ll & k) != 0) == ((ll & d) != 0));
            const bool mineBig = (kx > other);
            kx = (keepMax == mineBig) ? kx : other;
        }
    }
    const unsigned sord = (unsigned)(kx >> 32);
    const unsigned su = (sord & 0x80000000u) ? (sord & 0x7FFFFFFFu) : ~sord;
    const float sval = __uint_as_float(su);
    const int sidx = 1023 - (int)(kx & 1023u);

    const float kc0 = kcont[b * 3 + 0], kc1 = kcont[b * 3 + 1], kc2 = kcont[b * 3 + 2];
    const float w0 = wbr[b * 3 + 0], w1 = wbr[b * 3 + 1], w2 = wbr[b * 3 + 2];

    const float p = __expf(sval - maxv) * invden;
    const float rr = (float)ll + 0.5f;
    const float g0 = sigm(12.f * (kc0 - rr));
    const float g1 = sigm(12.f * (kc1 - rr));
    const float g2 = sigm(12.f * (kc2 - rr));
    float s0 = p * g0, s1 = p * g1, s2 = p * g2;
#pragma unroll
    for (int d = 1; d < 16; d <<= 1) {
        s0 += __shfl_xor(s0, d);
        s1 += __shfl_xor(s1, d);
        s2 += __shfl_xor(s2, d);
    }
    const float f0 = w0 / (s0 + 1e-8f);
    const float f1 = w1 / (s1 + 1e-8f);
    const float f2 = w2 / (s2 + 1e-8f);
    const float mycoef = p * (f0 * g0 + f1 * g1 + f2 * g2);

    const int gbase = lane & 48;
    const unsigned short* hbase = h + (long long)b * (N_ * DIM_) + lane * 8;
    float acc[8] = {0.f, 0.f, 0.f, 0.f, 0.f, 0.f, 0.f, 0.f};
#pragma unroll
    for (int r = 0; r < 16; ++r) {
        const float coef = __shfl(mycoef, gbase | r);
        const int idx = __shfl(sidx, gbase | r);
        const ushort4 h0 = *(const ushort4*)(hbase + (long long)idx * DIM_);
        const ushort4 h1 = *(const ushort4*)(hbase + (long long)idx * DIM_ + 4);
        acc[0] = fmaf(coef, bf2f(h0.x), acc[0]);
        acc[1] = fmaf(coef, bf2f(h0.y), acc[1]);
        acc[2] = fmaf(coef, bf2f(h0.z), acc[2]);
        acc[3] = fmaf(coef, bf2f(h0.w), acc[3]);
        acc[4] = fmaf(coef, bf2f(h1.x), acc[4]);
        acc[5] = fmaf(coef, bf2f(h1.y), acc[5]);
        acc[6] = fmaf(coef, bf2f(h1.z), acc[6]);
        acc[7] = fmaf(coef, bf2f(h1.w), acc[7]);
    }
    float* yp = y + (long long)row * DIM_ + lane * 8;
    *(float4*)(yp + 0) = make_float4(acc[0], acc[1], acc[2], acc[3]);
    *(float4*)(yp + 4) = make_float4(acc[4], acc[5], acc[6], acc[7]);
}

extern "C" void kernel_launch(void* const* d_in, const int* in_sizes, int n_in,
                              void* d_out, int out_size, void* d_ws, size_t ws_size,
                              hipStream_t stream) {
    const float* x     = (const float*)d_in[0];
    const float* fc1_w = (const float*)d_in[1];
    const float* fc1_b = (const float*)d_in[2];
    const float* fc2_w = (const float*)d_in[3];
    const float* fc2_b = (const float*)d_in[4];
    const float* k1_w  = (const float*)d_in[5];
    const float* k1_b  = (const float*)d_in[6];
    const float* k2_w  = (const float*)d_in[7];
    const float* k2_b  = (const float*)d_in[8];
    const float* w1_w  = (const float*)d_in[9];
    const float* w1_b  = (const float*)d_in[10];
    const float* w2_w  = (const float*)d_in[11];
    const float* w2_b  = (const float*)d_in[12];

    char* ws = (char*)d_ws;
    short* h1b    = (short*)(ws + 0);              // 33,554,432 (live fc1->fc2)
    float* simbuf = (float*)(ws + 0);              // 33,554,432 (reuse after fc2)
    short* xb     = (short*)(ws + 33554432);       // 8,388,608
    short* hb     = (short*)(ws + 67108864);       // 8,388,608
    short* w1b    = (short*)(ws + 75497472);       // 2,097,152
    short* w2b    = (short*)(ws + 77594624);       // 2,097,152
    float* ppart  = (float*)(ws + 79691776);       // 524,288
    float* kcont  = (float*)(ws + 80216064);       // 128
    float* wbr    = (float*)(ws + 80216192);       // 128

    float* y = (float*)d_out;

    // 0) fused prep: pooled partials + x->bf16 (blocks 0..255), weights->bf16 (256..511)
    prep_kernel<<<dim3(512), dim3(512), 0, stream>>>(x, ppart, xb, fc1_w, fc2_w, w1b, w2b);
    // 1) pooled reduce + head nets
    pool_heads_kernel<<<dim3(B_), dim3(512), 0, stream>>>(ppart, k1_w, k1_b, k2_w, k2_b,
                                                          w1_w, w1_b, w2_w, w2_b, kcont, wbr);
    // 2) h1 = relu(x @ fc1_w^T + b1) -> bf16    M=8192 N=2048 K=512 (128x128 tile)
    gemm_mfma<0, 128><<<dim3(HID_ / 128, ROWS_ / 128, 1), dim3(256), 0, stream>>>(
        xb, w1b, fc1_b, nullptr, h1b, ROWS_, HID_, DIM_, DIM_, DIM_, 0, 0, 0);
    // 3) h = h1 @ fc2_w^T + b2 -> bf16 direct   M=8192 N=512 K=2048 (128x64 tile, 512 blocks)
    gemm_mfma<1, 64><<<dim3(DIM_ / 64, ROWS_ / 128, 1), dim3(256), 0, stream>>>(
        h1b, w2b, fc2_b, nullptr, hb, ROWS_, DIM_, HID_, HID_, HID_, 0, 0, 0);
    // 4) sim[b] = hb[b] @ hb[b]^T -> fp32       M=N=1024 K=512, batch 8 (overwrites h1b)
    gemm_mfma<2, 128><<<dim3(N_ / 128, N_ / 128, B_), dim3(256), 0, stream>>>(
        hb, hb, nullptr, simbuf, nullptr, N_, N_, DIM_, DIM_, DIM_,
        (long long)N_ * DIM_, (long long)N_ * DIM_, (long long)N_ * N_);
    // 5) fused per-row top-16 + aggregate into output
    topk_agg_kernel<<<dim3(ROWS_ / 4), dim3(256), 0, stream>>>(
        simbuf, kcont, wbr, (const unsigned short*)hb, y);
}

// Round 11
// 219.802 us; speedup vs baseline: 1.0442x; 1.0442x over previous
//
#include <hip/hip_runtime.h>
#include <math.h>

#define DIM_ 512
#define HID_ 2048
#define B_ 8
#define N_ 1024
#define ROWS_ 8192   // B_*N_
#define TOPK 16      // exact: gate at rank>=16 is <= e^-54 (k<12), contribution ~1e-20

typedef __attribute__((ext_vector_type(8))) short short8;
typedef __attribute__((ext_vector_type(16))) float float16v;

__device__ __forceinline__ float sigm(float x) { return 1.f / (1.f + __expf(-x)); }

__device__ __forceinline__ short f2bf(float f) {           // RNE fp32 -> bf16
    unsigned u = __float_as_uint(f);
    u += 0x7FFF + ((u >> 16) & 1);
    return (short)(u >> 16);
}

__device__ __forceinline__ float bf2f(unsigned short s) {
    return __uint_as_float((unsigned)s << 16);
}

__device__ __forceinline__ unsigned f2ord(float f) {       // monotone fp32 -> u32
    unsigned u = __float_as_uint(f);
    return (u & 0x80000000u) ? ~u : (u | 0x80000000u);
}

__device__ __forceinline__ void gload16(const short* g, short* l) {
    __builtin_amdgcn_global_load_lds(
        (const __attribute__((address_space(1))) void*)g,
        (__attribute__((address_space(3))) void*)l, 16, 0, 0);
}

// ---------------- fused prep: pooled partials + x->bf16  |  weights->bf16 ----------------
__global__ __launch_bounds__(512)
void prep_kernel(const float* __restrict__ x, float* __restrict__ part, short* __restrict__ xb,
                 const float* __restrict__ w1, const float* __restrict__ w2,
                 short* __restrict__ o1, short* __restrict__ o2) {
    const int bx = blockIdx.x;
    if (bx < 256) {
        const int b = bx >> 5, chunk = bx & 31;
        const int c = threadIdx.x;                     // 512
        const long long base = ((long long)b * N_ + chunk * 32) * DIM_ + c;
        const float* xp = x + base;
        short* xo = xb + base;
        float s = 0.f;
        for (int n = 0; n < 32; ++n) {
            const float v = xp[(long long)n * DIM_];
            s += v;
            xo[(long long)n * DIM_] = f2bf(v);
        }
        part[(long long)bx * DIM_ + c] = s;
    } else {
        const int n4 = HID_ * DIM_ / 4;                // 262144 float4 per matrix
        int i = (bx - 256) * 2048 + threadIdx.x;
#pragma unroll
        for (int t = 0; t < 4; ++t, i += 512) {
            const float* in = (i < n4) ? w1 : w2;
            short* out = (i < n4) ? o1 : o2;
            const int j = (i < n4) ? i : (i - n4);
            const float4 v = *(const float4*)(in + (long long)j * 4);
            short4 o;
            o.x = f2bf(v.x); o.y = f2bf(v.y); o.z = f2bf(v.z); o.w = f2bf(v.w);
            *(short4*)(out + (long long)j * 4) = o;
        }
    }
}

// ---------------- pooled reduce + head nets (fused): k_cont (B,3), w (B,3) ----------------
__global__ __launch_bounds__(512)
void pool_heads_kernel(const float* __restrict__ part,
                       const float* __restrict__ k1w, const float* __restrict__ k1b,
                       const float* __restrict__ k2w, const float* __restrict__ k2b,
                       const float* __restrict__ w1w, const float* __restrict__ w1b,
                       const float* __restrict__ w2w, const float* __restrict__ w2b,
                       float* __restrict__ kcont, float* __restrict__ wbr) {
    const int b = blockIdx.x;
    const int t = threadIdx.x;                     // 512
    __shared__ float sp[DIM_];
    __shared__ float kh[128], wh[128];
    __shared__ float wraw[4];
    float s = 0.f;
    for (int g = 0; g < 32; ++g) s += part[((long long)b * 32 + g) * DIM_ + t];
    sp[t] = s * (1.f / 1024.f);
    __syncthreads();
    if (t < 128) {
        float ak = k1b[t], aw = w1b[t];
        for (int k = 0; k < DIM_; ++k) {
            const float pv = sp[k];
            ak = fmaf(pv, k1w[t * DIM_ + k], ak);
            aw = fmaf(pv, w1w[t * DIM_ + k], aw);
        }
        kh[t] = fmaxf(ak, 0.f);
        wh[t] = fmaxf(aw, 0.f);
    }
    __syncthreads();
    if (t < 3) {
        float rk = k2b[t], rw = w2b[t];
        for (int k = 0; k < 128; ++k) {
            rk = fmaf(kh[k], k2w[t * 128 + k], rk);
            rw = fmaf(wh[k], w2w[t * 128 + k], rw);
        }
        kcont[b * 3 + t] = 1.f + 11.f * sigm(rk);
        wraw[t] = rw;
    }
    __syncthreads();
    if (t == 0) {
        const float m = fmaxf(wraw[0], fmaxf(wraw[1], wraw[2]));
        const float e0 = __expf(wraw[0] - m), e1 = __expf(wraw[1] - m), e2 = __expf(wraw[2] - m);
        const float inv = 1.f / (e0 + e1 + e2);
        wbr[b * 3 + 0] = e0 * inv;
        wbr[b * 3 + 1] = e1 * inv;
        wbr[b * 3 + 2] = e2 * inv;
    }
}

// ---------------- bf16 MFMA NT GEMM, 32x32x16, 128xBN tile, XCD-swizzled ----------------
// BN=128: each wave 64x64 = 2x2 frags.  BN=64: each wave 64x32 = 2x1 frags.
// SWZ=0: m-tile = id % gridDim.y -> all n-blocks of an m-tile share an XCD
//        (A-tile fetched once per XCD; workgroup->XCD is round-robin mod 8).
// SWZ=1: batch = id % gridDim.z -> each batch L2-resident on one XCD (sim).
// A/B frag: m|n = lane&31, k = (lane>>5)*8 + j.  C/D: col=lane&31,
// row=(reg&3)+8*(reg>>2)+4*(lane>>5)  [m74/m101-verified].
// OUTMODE: 0 = bf16 out, bias+relu; 1 = bf16 out, bias; 2 = fp32 raw (no bias)
template<int OUTMODE, int BN, int SWZ>
__global__ __launch_bounds__(256)
void gemm_mfma(const short* __restrict__ A, const short* __restrict__ Bm,
               const float* __restrict__ bias,
               float* __restrict__ outF, short* __restrict__ outB,
               int M, int N, int K, int lda, int ldb,
               long long sA, long long sB, long long sC) {
    constexpr int NJ = BN / 64;             // j-frags per wave (2 or 1)
    int bz, mi, ni;
    if (SWZ == 1) {
        const int id = blockIdx.x + gridDim.x * (blockIdx.y + gridDim.y * blockIdx.z);
        bz = id % gridDim.z;
        const int r = id / gridDim.z;
        ni = r % gridDim.x;
        mi = r / gridDim.x;
    } else {
        const int t = blockIdx.x + gridDim.x * blockIdx.y;
        bz = blockIdx.z;
        mi = t % gridDim.y;
        ni = t / gridDim.y;
    }
    A  += (long long)bz * sA;
    Bm += (long long)bz * sB;

    __shared__ short As[128 * 64];
    __shared__ short Bs[BN * 64];

    const int tid = threadIdx.x;
    const int lane = tid & 63;
    const int wv = tid >> 6;                // 0..3
    const int m0 = mi * 128;
    const int n0 = ni * BN;

    const int lrow = lane >> 3;             // 0..7
    const int cg = (lane & 7) ^ lrow;       // XOR swizzle

    const int ml = (wv & 1) * 64;
    const int nl = (wv >> 1) * (BN / 2);    // BN=128 -> 64, BN=64 -> 32
    const int fr = lane & 31;               // fragment row/col (m or n)
    const int khh = lane >> 5;              // k-half 0..1

    float16v acc[2][NJ];
#pragma unroll
    for (int i = 0; i < 2; ++i)
#pragma unroll
        for (int j = 0; j < NJ; ++j)
#pragma unroll
            for (int r = 0; r < 16; ++r) acc[i][j][r] = 0.f;

    for (int k0 = 0; k0 < K; k0 += 64) {
        __syncthreads();
#pragma unroll
        for (int i = 0; i < 4; ++i) {
            const int rloc = wv * 32 + i * 8 + lrow;
            gload16(A + (long long)(m0 + rloc) * lda + (k0 + cg * 8),
                    &As[(wv * 32 + i * 8) * 64]);
        }
#pragma unroll
        for (int i = 0; i < BN / 32; ++i) {
            const int rloc = wv * (BN / 4) + i * 8 + lrow;
            gload16(Bm + (long long)(n0 + rloc) * ldb + (k0 + cg * 8),
                    &Bs[(wv * (BN / 4) + i * 8) * 64]);
        }
        __syncthreads();
#pragma unroll
        for (int c = 0; c < 4; ++c) {           // 4 ksteps of K=16
            const int ch = c * 2 + khh;         // 8-elem chunk index
            short8 af[2], bfr[NJ];
#pragma unroll
            for (int i = 0; i < 2; ++i) {
                const int m = ml + i * 32 + fr;
                af[i] = *(const short8*)&As[m * 64 + ((ch ^ (m & 7)) * 8)];
            }
#pragma unroll
            for (int j = 0; j < NJ; ++j) {
                const int n = nl + j * 32 + fr;
                bfr[j] = *(const short8*)&Bs[n * 64 + ((ch ^ (n & 7)) * 8)];
            }
#pragma unroll
            for (int i = 0; i < 2; ++i)
#pragma unroll
                for (int j = 0; j < NJ; ++j)
                    acc[i][j] = __builtin_amdgcn_mfma_f32_32x32x16_bf16(
                        af[i], bfr[j], acc[i][j], 0, 0, 0);
        }
    }

    const long long outOfs = (long long)bz * sC;
#pragma unroll
    for (int i = 0; i < 2; ++i) {
#pragma unroll
        for (int j = 0; j < NJ; ++j) {
            const int ng = n0 + nl + j * 32 + fr;
            float bv = 0.f;
            if (OUTMODE != 2) bv = bias[ng];
#pragma unroll
            for (int r = 0; r < 16; ++r) {
                const int mg = m0 + ml + i * 32 + (r & 3) + 8 * (r >> 2) + 4 * khh;
                float v = acc[i][j][r] + bv;
                if (OUTMODE == 0) v = fmaxf(v, 0.f);
                const long long idx = outOfs + (long long)mg * N + ng;
                if (OUTMODE == 2) outF[idx] = v;
                else              outB[idx] = f2bf(v);
            }
        }
    }
}

// ---------------- fused per-row top-16 + aggregate (two-phase exact) ----------------
__global__ __launch_bounds__(256)
void topk_agg_kernel(const float* __restrict__ sim,
                     const float* __restrict__ kcont, const float* __restrict__ wbr,
                     const unsigned short* __restrict__ h, float* __restrict__ y) {
    const int wv = threadIdx.x >> 6;
    const int lane = threadIdx.x & 63;
    const int ll = lane & 15;
    const int row = blockIdx.x * 4 + wv;          // 2048 blocks * 4 waves
    const int b = row >> 10;
    const float* srow = sim + (long long)row * N_;

    float f[16];
    const int base = lane * 16;
#pragma unroll
    for (int q = 0; q < 4; ++q) {
        const float4 v = *(const float4*)(srow + base + q * 4);
        f[q * 4 + 0] = v.x; f[q * 4 + 1] = v.y; f[q * 4 + 2] = v.z; f[q * 4 + 3] = v.w;
    }

    // row max
    float lmax = f[0];
#pragma unroll
    for (int j = 1; j < 16; ++j) lmax = fmaxf(lmax, f[j]);
#pragma unroll
    for (int d = 32; d > 0; d >>= 1) lmax = fmaxf(lmax, __shfl_xor(lmax, d));
    const float maxv = lmax;

    // softmax denominator (full row, exact fp32)
    float lsum = 0.f;
#pragma unroll
    for (int j = 0; j < 16; ++j) lsum += __expf(f[j] - maxv);
#pragma unroll
    for (int d = 32; d > 0; d >>= 1) lsum += __shfl_xor(lsum, d);
    const float invden = 1.f / lsum;

    // ---- Phase A: u32 keys ----
    unsigned key[16];
#pragma unroll
    for (int j = 0; j < 16; ++j)
        key[j] = (f2ord(f[j]) & 0xFFFFFC00u) | (unsigned)(1023 - (base + j));

#pragma unroll
    for (int k = 2; k <= 16; k <<= 1) {
#pragma unroll
        for (int j = k >> 1; j > 0; j >>= 1) {
#pragma unroll
            for (int i = 0; i < 16; ++i) {
                const int l = i ^ j;
                if (l > i) {
                    const bool desc = ((i & k) == 0);
                    const unsigned a = key[i], bk = key[l];
                    const unsigned hi = (a > bk) ? a : bk;
                    const unsigned lo = (a > bk) ? bk : a;
                    key[i] = desc ? hi : lo;
                    key[l] = desc ? lo : hi;
                }
            }
        }
    }

#pragma unroll
    for (int d = 1; d < 64; d <<= 1) {
        unsigned other[16];
#pragma unroll
        for (int i = 0; i < 16; ++i)
            other[i] = __shfl_xor(key[15 - i], d);
#pragma unroll
        for (int i = 0; i < 16; ++i)
            key[i] = (key[i] > other[i]) ? key[i] : other[i];
#pragma unroll
        for (int j = 8; j > 0; j >>= 1) {
#pragma unroll
            for (int i = 0; i < 16; ++i) {
                if ((i & j) == 0) {
                    const unsigned a = key[i], bk = key[i | j];
                    key[i]     = (a > bk) ? a : bk;
                    key[i | j] = (a > bk) ? bk : a;
                }
            }
        }
    }

    // ---- Phase B: exact order of the 16 survivors ----
    unsigned k32 = key[0];
#pragma unroll
    for (int j = 1; j < 16; ++j) k32 = (ll == j) ? key[j] : k32;
    const int myidx = 1023 - (int)(k32 & 1023u);
    const float myval = srow[myidx];

    unsigned long long kx = ((unsigned long long)f2ord(myval) << 32)
                          | (unsigned)(1023 - myidx);
#pragma unroll
    for (int k = 2; k <= 16; k <<= 1) {
#pragma unroll
        for (int d = k >> 1; d > 0; d >>= 1) {
            const unsigned long long other = __shfl_xor(kx, d);
            const bool keepMax = (((ll & k) != 0) == ((ll & d) != 0));
            const bool mineBig = (kx > other);
            kx = (keepMax == mineBig) ? kx : other;
        }
    }
    const unsigned sord = (unsigned)(kx >> 32);
    const unsigned su = (sord & 0x80000000u) ? (sord & 0x7FFFFFFFu) : ~sord;
    const float sval = __uint_as_float(su);
    const int sidx = 1023 - (int)(kx & 1023u);

    const float kc0 = kcont[b * 3 + 0], kc1 = kcont[b * 3 + 1], kc2 = kcont[b * 3 + 2];
    const float w0 = wbr[b * 3 + 0], w1 = wbr[b * 3 + 1], w2 = wbr[b * 3 + 2];

    const float p = __expf(sval - maxv) * invden;
    const float rr = (float)ll + 0.5f;
    const float g0 = sigm(12.f * (kc0 - rr));
    const float g1 = sigm(12.f * (kc1 - rr));
    const float g2 = sigm(12.f * (kc2 - rr));
    float s0 = p * g0, s1 = p * g1, s2 = p * g2;
#pragma unroll
    for (int d = 1; d < 16; d <<= 1) {
        s0 += __shfl_xor(s0, d);
        s1 += __shfl_xor(s1, d);
        s2 += __shfl_xor(s2, d);
    }
    const float f0 = w0 / (s0 + 1e-8f);
    const float f1 = w1 / (s1 + 1e-8f);
    const float f2 = w2 / (s2 + 1e-8f);
    const float mycoef = p * (f0 * g0 + f1 * g1 + f2 * g2);

    const int gbase = lane & 48;
    const unsigned short* hbase = h + (long long)b * (N_ * DIM_) + lane * 8;
    float acc[8] = {0.f, 0.f, 0.f, 0.f, 0.f, 0.f, 0.f, 0.f};
#pragma unroll
    for (int r = 0; r < 16; ++r) {
        const float coef = __shfl(mycoef, gbase | r);
        const int idx = __shfl(sidx, gbase | r);
        const ushort4 h0 = *(const ushort4*)(hbase + (long long)idx * DIM_);
        const ushort4 h1 = *(const ushort4*)(hbase + (long long)idx * DIM_ + 4);
        acc[0] = fmaf(coef, bf2f(h0.x), acc[0]);
        acc[1] = fmaf(coef, bf2f(h0.y), acc[1]);
        acc[2] = fmaf(coef, bf2f(h0.z), acc[2]);
        acc[3] = fmaf(coef, bf2f(h0.w), acc[3]);
        acc[4] = fmaf(coef, bf2f(h1.x), acc[4]);
        acc[5] = fmaf(coef, bf2f(h1.y), acc[5]);
        acc[6] = fmaf(coef, bf2f(h1.z), acc[6]);
        acc[7] = fmaf(coef, bf2f(h1.w), acc[7]);
    }
    float* yp = y + (long long)row * DIM_ + lane * 8;
    *(float4*)(yp + 0) = make_float4(acc[0], acc[1], acc[2], acc[3]);
    *(float4*)(yp + 4) = make_float4(acc[4], acc[5], acc[6], acc[7]);
}

extern "C" void kernel_launch(void* const* d_in, const int* in_sizes, int n_in,
                              void* d_out, int out_size, void* d_ws, size_t ws_size,
                              hipStream_t stream) {
    const float* x     = (const float*)d_in[0];
    const float* fc1_w = (const float*)d_in[1];
    const float* fc1_b = (const float*)d_in[2];
    const float* fc2_w = (const float*)d_in[3];
    const float* fc2_b = (const float*)d_in[4];
    const float* k1_w  = (const float*)d_in[5];
    const float* k1_b  = (const float*)d_in[6];
    const float* k2_w  = (const float*)d_in[7];
    const float* k2_b  = (const float*)d_in[8];
    const float* w1_w  = (const float*)d_in[9];
    const float* w1_b  = (const float*)d_in[10];
    const float* w2_w  = (const float*)d_in[11];
    const float* w2_b  = (const float*)d_in[12];

    char* ws = (char*)d_ws;
    short* h1b    = (short*)(ws + 0);              // 33,554,432 (live fc1->fc2)
    float* simbuf = (float*)(ws + 0);              // 33,554,432 (reuse after fc2)
    short* xb     = (short*)(ws + 33554432);       // 8,388,608
    short* hb     = (short*)(ws + 67108864);       // 8,388,608
    short* w1b    = (short*)(ws + 75497472);       // 2,097,152
    short* w2b    = (short*)(ws + 77594624);       // 2,097,152
    float* ppart  = (float*)(ws + 79691776);       // 524,288
    float* kcont  = (float*)(ws + 80216064);       // 128
    float* wbr    = (float*)(ws + 80216192);       // 128

    float* y = (float*)d_out;

    // 0) fused prep: pooled partials + x->bf16 (blocks 0..255), weights->bf16 (256..511)
    prep_kernel<<<dim3(512), dim3(512), 0, stream>>>(x, ppart, xb, fc1_w, fc2_w, w1b, w2b);
    // 1) pooled reduce + head nets
    pool_heads_kernel<<<dim3(B_), dim3(512), 0, stream>>>(ppart, k1_w, k1_b, k2_w, k2_b,
                                                          w1_w, w1_b, w2_w, w2_b, kcont, wbr);
    // 2) h1 = relu(x @ fc1_w^T + b1) -> bf16    M=8192 N=2048 K=512 (128x128, m-XCD swizzle)
    gemm_mfma<0, 128, 0><<<dim3(HID_ / 128, ROWS_ / 128, 1), dim3(256), 0, stream>>>(
        xb, w1b, fc1_b, nullptr, h1b, ROWS_, HID_, DIM_, DIM_, DIM_, 0, 0, 0);
    // 3) h = h1 @ fc2_w^T + b2 -> bf16 direct   M=8192 N=512 K=2048 (128x64, m-XCD swizzle)
    gemm_mfma<1, 64, 0><<<dim3(DIM_ / 64, ROWS_ / 128, 1), dim3(256), 0, stream>>>(
        h1b, w2b, fc2_b, nullptr, hb, ROWS_, DIM_, HID_, HID_, HID_, 0, 0, 0);
    // 4) sim[b] = hb[b] @ hb[b]^T -> fp32       M=N=1024 K=512, batch 8 (batch-XCD swizzle)
    gemm_mfma<2, 128, 1><<<dim3(N_ / 128, N_ / 128, B_), dim3(256), 0, stream>>>(
        hb, hb, nullptr, simbuf, nullptr, N_, N_, DIM_, DIM_, DIM_,
        (long long)N_ * DIM_, (long long)N_ * DIM_, (long long)N_ * N_);
    // 5) fused per-row top-16 + aggregate into output
    topk_agg_kernel<<<dim3(ROWS_ / 4), dim3(256), 0, stream>>>(
        simbuf, kcont, wbr, (const unsigned short*)hb, y);
}

// Round 12
// 218.880 us; speedup vs baseline: 1.0486x; 1.0042x over previous
//
#include <hip/hip_runtime.h>
#include <math.h>

#define DIM_ 512
#define HID_ 2048
#define B_ 8
#define N_ 1024
#define ROWS_ 8192   // B_*N_
#define TOPK 16      // exact: gate at rank>=16 is <= e^-54 (k<12), contribution ~1e-20

typedef __attribute__((ext_vector_type(8))) short short8;
typedef __attribute__((ext_vector_type(16))) float float16v;

__device__ __forceinline__ float sigm(float x) { return 1.f / (1.f + __expf(-x)); }

__device__ __forceinline__ short f2bf(float f) {           // RNE fp32 -> bf16
    unsigned u = __float_as_uint(f);
    u += 0x7FFF + ((u >> 16) & 1);
    return (short)(u >> 16);
}

__device__ __forceinline__ float bf2f(unsigned short s) {
    return __uint_as_float((unsigned)s << 16);
}

__device__ __forceinline__ unsigned f2ord(float f) {       // monotone fp32 -> u32
    unsigned u = __float_as_uint(f);
    return (u & 0x80000000u) ? ~u : (u | 0x80000000u);
}

__device__ __forceinline__ void gload16(const short* g, short* l) {
    __builtin_amdgcn_global_load_lds(
        (const __attribute__((address_space(1))) void*)g,
        (__attribute__((address_space(3))) void*)l, 16, 0, 0);
}

// ---------------- fused prep: pooled partials + x->bf16  |  weights->bf16 ----------------
__global__ __launch_bounds__(512)
void prep_kernel(const float* __restrict__ x, float* __restrict__ part, short* __restrict__ xb,
                 const float* __restrict__ w1, const float* __restrict__ w2,
                 short* __restrict__ o1, short* __restrict__ o2) {
    const int bx = blockIdx.x;
    if (bx < 256) {
        const int b = bx >> 5, chunk = bx & 31;
        const int c = threadIdx.x;                     // 512
        const long long base = ((long long)b * N_ + chunk * 32) * DIM_ + c;
        const float* xp = x + base;
        short* xo = xb + base;
        float s = 0.f;
        for (int n = 0; n < 32; ++n) {
            const float v = xp[(long long)n * DIM_];
            s += v;
            xo[(long long)n * DIM_] = f2bf(v);
        }
        part[(long long)bx * DIM_ + c] = s;
    } else {
        const int n4 = HID_ * DIM_ / 4;                // 262144 float4 per matrix
        int i = (bx - 256) * 2048 + threadIdx.x;
#pragma unroll
        for (int t = 0; t < 4; ++t, i += 512) {
            const float* in = (i < n4) ? w1 : w2;
            short* out = (i < n4) ? o1 : o2;
            const int j = (i < n4) ? i : (i - n4);
            const float4 v = *(const float4*)(in + (long long)j * 4);
            short4 o;
            o.x = f2bf(v.x); o.y = f2bf(v.y); o.z = f2bf(v.z); o.w = f2bf(v.w);
            *(short4*)(out + (long long)j * 4) = o;
        }
    }
}

// ---------------- pooled reduce + head nets (fused): k_cont (B,3), w (B,3) ----------------
__global__ __launch_bounds__(512)
void pool_heads_kernel(const float* __restrict__ part,
                       const float* __restrict__ k1w, const float* __restrict__ k1b,
                       const float* __restrict__ k2w, const float* __restrict__ k2b,
                       const float* __restrict__ w1w, const float* __restrict__ w1b,
                       const float* __restrict__ w2w, const float* __restrict__ w2b,
                       float* __restrict__ kcont, float* __restrict__ wbr) {
    const int b = blockIdx.x;
    const int t = threadIdx.x;                     // 512
    __shared__ float sp[DIM_];
    __shared__ float kh[128], wh[128];
    __shared__ float wraw[4];
    float s = 0.f;
    for (int g = 0; g < 32; ++g) s += part[((long long)b * 32 + g) * DIM_ + t];
    sp[t] = s * (1.f / 1024.f);
    __syncthreads();
    if (t < 128) {
        float ak = k1b[t], aw = w1b[t];
        for (int k = 0; k < DIM_; ++k) {
            const float pv = sp[k];
            ak = fmaf(pv, k1w[t * DIM_ + k], ak);
            aw = fmaf(pv, w1w[t * DIM_ + k], aw);
        }
        kh[t] = fmaxf(ak, 0.f);
        wh[t] = fmaxf(aw, 0.f);
    }
    __syncthreads();
    if (t < 3) {
        float rk = k2b[t], rw = w2b[t];
        for (int k = 0; k < 128; ++k) {
            rk = fmaf(kh[k], k2w[t * 128 + k], rk);
            rw = fmaf(wh[k], w2w[t * 128 + k], rw);
        }
        kcont[b * 3 + t] = 1.f + 11.f * sigm(rk);
        wraw[t] = rw;
    }
    __syncthreads();
    if (t == 0) {
        const float m = fmaxf(wraw[0], fmaxf(wraw[1], wraw[2]));
        const float e0 = __expf(wraw[0] - m), e1 = __expf(wraw[1] - m), e2 = __expf(wraw[2] - m);
        const float inv = 1.f / (e0 + e1 + e2);
        wbr[b * 3 + 0] = e0 * inv;
        wbr[b * 3 + 1] = e1 * inv;
        wbr[b * 3 + 2] = e2 * inv;
    }
}

// ---------------- bf16 MFMA NT GEMM, 32x32x16, 128xBN tile, XCD-swizzled ----------------
// (unchanged from R11 — verified)
template<int OUTMODE, int BN, int SWZ>
__global__ __launch_bounds__(256)
void gemm_mfma(const short* __restrict__ A, const short* __restrict__ Bm,
               const float* __restrict__ bias,
               float* __restrict__ outF, short* __restrict__ outB,
               int M, int N, int K, int lda, int ldb,
               long long sA, long long sB, long long sC) {
    constexpr int NJ = BN / 64;             // j-frags per wave (2 or 1)
    int bz, mi, ni;
    if (SWZ == 1) {
        const int id = blockIdx.x + gridDim.x * (blockIdx.y + gridDim.y * blockIdx.z);
        bz = id % gridDim.z;
        const int r = id / gridDim.z;
        ni = r % gridDim.x;
        mi = r / gridDim.x;
    } else {
        const int t = blockIdx.x + gridDim.x * blockIdx.y;
        bz = blockIdx.z;
        mi = t % gridDim.y;
        ni = t / gridDim.y;
    }
    A  += (long long)bz * sA;
    Bm += (long long)bz * sB;

    __shared__ short As[128 * 64];
    __shared__ short Bs[BN * 64];

    const int tid = threadIdx.x;
    const int lane = tid & 63;
    const int wv = tid >> 6;                // 0..3
    const int m0 = mi * 128;
    const int n0 = ni * BN;

    const int lrow = lane >> 3;             // 0..7
    const int cg = (lane & 7) ^ lrow;       // XOR swizzle

    const int ml = (wv & 1) * 64;
    const int nl = (wv >> 1) * (BN / 2);    // BN=128 -> 64, BN=64 -> 32
    const int fr = lane & 31;               // fragment row/col (m or n)
    const int khh = lane >> 5;              // k-half 0..1

    float16v acc[2][NJ];
#pragma unroll
    for (int i = 0; i < 2; ++i)
#pragma unroll
        for (int j = 0; j < NJ; ++j)
#pragma unroll
            for (int r = 0; r < 16; ++r) acc[i][j][r] = 0.f;

    for (int k0 = 0; k0 < K; k0 += 64) {
        __syncthreads();
#pragma unroll
        for (int i = 0; i < 4; ++i) {
            const int rloc = wv * 32 + i * 8 + lrow;
            gload16(A + (long long)(m0 + rloc) * lda + (k0 + cg * 8),
                    &As[(wv * 32 + i * 8) * 64]);
        }
#pragma unroll
        for (int i = 0; i < BN / 32; ++i) {
            const int rloc = wv * (BN / 4) + i * 8 + lrow;
            gload16(Bm + (long long)(n0 + rloc) * ldb + (k0 + cg * 8),
                    &Bs[(wv * (BN / 4) + i * 8) * 64]);
        }
        __syncthreads();
#pragma unroll
        for (int c = 0; c < 4; ++c) {           // 4 ksteps of K=16
            const int ch = c * 2 + khh;         // 8-elem chunk index
            short8 af[2], bfr[NJ];
#pragma unroll
            for (int i = 0; i < 2; ++i) {
                const int m = ml + i * 32 + fr;
                af[i] = *(const short8*)&As[m * 64 + ((ch ^ (m & 7)) * 8)];
            }
#pragma unroll
            for (int j = 0; j < NJ; ++j) {
                const int n = nl + j * 32 + fr;
                bfr[j] = *(const short8*)&Bs[n * 64 + ((ch ^ (n & 7)) * 8)];
            }
#pragma unroll
            for (int i = 0; i < 2; ++i)
#pragma unroll
                for (int j = 0; j < NJ; ++j)
                    acc[i][j] = __builtin_amdgcn_mfma_f32_32x32x16_bf16(
                        af[i], bfr[j], acc[i][j], 0, 0, 0);
        }
    }

    const long long outOfs = (long long)bz * sC;
#pragma unroll
    for (int i = 0; i < 2; ++i) {
#pragma unroll
        for (int j = 0; j < NJ; ++j) {
            const int ng = n0 + nl + j * 32 + fr;
            float bv = 0.f;
            if (OUTMODE != 2) bv = bias[ng];
#pragma unroll
            for (int r = 0; r < 16; ++r) {
                const int mg = m0 + ml + i * 32 + (r & 3) + 8 * (r >> 2) + 4 * khh;
                float v = acc[i][j][r] + bv;
                if (OUTMODE == 0) v = fmaxf(v, 0.f);
                const long long idx = outOfs + (long long)mg * N + ng;
                if (OUTMODE == 2) outF[idx] = v;
                else              outB[idx] = f2bf(v);
            }
        }
    }
}

// ---------------- fused per-row top-16 + aggregate, TWO rows per wave ----------------
// Phase A (per row, interleaved for ILP): u32-key local sort + 6 merge rounds.
// Phase B: 16-lane groups {0,2} order row A, {1,3} order row B (exact u64 keys).
// Gather: broadcast (idx,coef) from matching half-wave groups, write both rows.
__global__ __launch_bounds__(256)
void topk_agg_kernel(const float* __restrict__ sim,
                     const float* __restrict__ kcont, const float* __restrict__ wbr,
                     const unsigned short* __restrict__ h, float* __restrict__ y) {
    const int wv = threadIdx.x >> 6;
    const int lane = threadIdx.x & 63;
    const int ll = lane & 15;
    const int row0 = blockIdx.x * 8 + wv * 2;     // 1024 blocks * 4 waves * 2 rows
    const int b = row0 >> 10;                     // row0 even -> row0+1 same batch
    const float* srowA = sim + (long long)row0 * N_;
    const float* srowB = srowA + N_;

    const int base = lane * 16;
    float fA[16], fB[16];
#pragma unroll
    for (int q = 0; q < 4; ++q) {
        const float4 va = *(const float4*)(srowA + base + q * 4);
        const float4 vb = *(const float4*)(srowB + base + q * 4);
        fA[q * 4 + 0] = va.x; fA[q * 4 + 1] = va.y; fA[q * 4 + 2] = va.z; fA[q * 4 + 3] = va.w;
        fB[q * 4 + 0] = vb.x; fB[q * 4 + 1] = vb.y; fB[q * 4 + 2] = vb.z; fB[q * 4 + 3] = vb.w;
    }

    // row max (both rows, interleaved)
    float mA = fA[0], mB = fB[0];
#pragma unroll
    for (int j = 1; j < 16; ++j) { mA = fmaxf(mA, fA[j]); mB = fmaxf(mB, fB[j]); }
#pragma unroll
    for (int d = 32; d > 0; d >>= 1) {
        mA = fmaxf(mA, __shfl_xor(mA, d));
        mB = fmaxf(mB, __shfl_xor(mB, d));
    }
    const float maxvA = mA, maxvB = mB;

    // softmax denominators
    float sAo = 0.f, sBo = 0.f;
#pragma unroll
    for (int j = 0; j < 16; ++j) { sAo += __expf(fA[j] - maxvA); sBo += __expf(fB[j] - maxvB); }
#pragma unroll
    for (int d = 32; d > 0; d >>= 1) {
        sAo += __shfl_xor(sAo, d);
        sBo += __shfl_xor(sBo, d);
    }
    const float invdenA = 1.f / sAo, invdenB = 1.f / sBo;

    // ---- Phase A: u32 keys, both rows ----
    unsigned keyA[16], keyB[16];
#pragma unroll
    for (int j = 0; j < 16; ++j) {
        keyA[j] = (f2ord(fA[j]) & 0xFFFFFC00u) | (unsigned)(1023 - (base + j));
        keyB[j] = (f2ord(fB[j]) & 0xFFFFFC00u) | (unsigned)(1023 - (base + j));
    }

    // lane-local bitonic sort, descending (interleaved)
#pragma unroll
    for (int k = 2; k <= 16; k <<= 1) {
#pragma unroll
        for (int j = k >> 1; j > 0; j >>= 1) {
#pragma unroll
            for (int i = 0; i < 16; ++i) {
                const int l = i ^ j;
                if (l > i) {
                    const bool desc = ((i & k) == 0);
                    {
                        const unsigned a = keyA[i], bk = keyA[l];
                        const unsigned hi = (a > bk) ? a : bk;
                        const unsigned lo = (a > bk) ? bk : a;
                        keyA[i] = desc ? hi : lo;
                        keyA[l] = desc ? lo : hi;
                    }
                    {
                        const unsigned a = keyB[i], bk = keyB[l];
                        const unsigned hi = (a > bk) ? a : bk;
                        const unsigned lo = (a > bk) ? bk : a;
                        keyB[i] = desc ? hi : lo;
                        keyB[l] = desc ? lo : hi;
                    }
                }
            }
        }
    }

    // 6 merge rounds (interleaved)
#pragma unroll
    for (int d = 1; d < 64; d <<= 1) {
        unsigned oA[16], oB[16];
#pragma unroll
        for (int i = 0; i < 16; ++i) {
            oA[i] = __shfl_xor(keyA[15 - i], d);
            oB[i] = __shfl_xor(keyB[15 - i], d);
        }
#pragma unroll
        for (int i = 0; i < 16; ++i) {
            keyA[i] = (keyA[i] > oA[i]) ? keyA[i] : oA[i];
            keyB[i] = (keyB[i] > oB[i]) ? keyB[i] : oB[i];
        }
#pragma unroll
        for (int j = 8; j > 0; j >>= 1) {
#pragma unroll
            for (int i = 0; i < 16; ++i) {
                if ((i & j) == 0) {
                    {
                        const unsigned a = keyA[i], bk = keyA[i | j];
                        keyA[i]     = (a > bk) ? a : bk;
                        keyA[i | j] = (a > bk) ? bk : a;
                    }
                    {
                        const unsigned a = keyB[i], bk = keyB[i | j];
                        keyB[i]     = (a > bk) ? a : bk;
                        keyB[i | j] = (a > bk) ? bk : a;
                    }
                }
            }
        }
    }

    // ---- Phase B: groups {0,2} -> row A, {1,3} -> row B ----
    const int rowSel = (lane >> 4) & 1;
    unsigned k32 = 0;
#pragma unroll
    for (int j = 0; j < 16; ++j) {
        const unsigned sel = rowSel ? keyB[j] : keyA[j];
        k32 = (ll == j) ? sel : k32;
    }
    const int myidx = 1023 - (int)(k32 & 1023u);
    const float* srow = rowSel ? srowB : srowA;
    const float myval = srow[myidx];                 // L1-hot exact fp32

    unsigned long long kx = ((unsigned long long)f2ord(myval) << 32)
                          | (unsigned)(1023 - myidx);
#pragma unroll
    for (int k = 2; k <= 16; k <<= 1) {
#pragma unroll
        for (int d = k >> 1; d > 0; d >>= 1) {
            const unsigned long long other = __shfl_xor(kx, d);
            const bool keepMax = (((ll & k) != 0) == ((ll & d) != 0));
            const bool mineBig = (kx > other);
            kx = (keepMax == mineBig) ? kx : other;
        }
    }
    const unsigned sord = (unsigned)(kx >> 32);
    const unsigned su = (sord & 0x80000000u) ? (sord & 0x7FFFFFFFu) : ~sord;
    const float sval = __uint_as_float(su);
    const int sidx = 1023 - (int)(kx & 1023u);

    const float kc0 = kcont[b * 3 + 0], kc1 = kcont[b * 3 + 1], kc2 = kcont[b * 3 + 2];
    const float w0 = wbr[b * 3 + 0], w1 = wbr[b * 3 + 1], w2 = wbr[b * 3 + 2];

    const float mv = rowSel ? maxvB : maxvA;
    const float ivd = rowSel ? invdenB : invdenA;
    const float p = __expf(sval - mv) * ivd;
    const float rr = (float)ll + 0.5f;
    const float g0 = sigm(12.f * (kc0 - rr));
    const float g1 = sigm(12.f * (kc1 - rr));
    const float g2 = sigm(12.f * (kc2 - rr));
    float s0 = p * g0, s1 = p * g1, s2 = p * g2;
#pragma unroll
    for (int d = 1; d < 16; d <<= 1) {
        s0 += __shfl_xor(s0, d);
        s1 += __shfl_xor(s1, d);
        s2 += __shfl_xor(s2, d);
    }
    const float f0 = w0 / (s0 + 1e-8f);
    const float f1 = w1 / (s1 + 1e-8f);
    const float f2 = w2 / (s2 + 1e-8f);
    const float mycoef = p * (f0 * g0 + f1 * g1 + f2 * g2);

    // gather both rows: row A coefs live in groups 0,2 (lanes (lane&32)|r),
    // row B in groups 1,3 (lanes (lane&32)|16|r)
    const unsigned short* hbase = h + (long long)b * (N_ * DIM_) + lane * 8;
    float accA[8] = {0.f, 0.f, 0.f, 0.f, 0.f, 0.f, 0.f, 0.f};
    float accB[8] = {0.f, 0.f, 0.f, 0.f, 0.f, 0.f, 0.f, 0.f};
    const int half = lane & 32;
#pragma unroll
    for (int r = 0; r < 16; ++r) {
        const float cA = __shfl(mycoef, half | r);
        const int   iA = __shfl(sidx,  half | r);
        const float cB = __shfl(mycoef, half | 16 | r);
        const int   iB = __shfl(sidx,  half | 16 | r);
        const ushort4 a0 = *(const ushort4*)(hbase + (long long)iA * DIM_);
        const ushort4 a1 = *(const ushort4*)(hbase + (long long)iA * DIM_ + 4);
        const ushort4 b0 = *(const ushort4*)(hbase + (long long)iB * DIM_);
        const ushort4 b1 = *(const ushort4*)(hbase + (long long)iB * DIM_ + 4);
        accA[0] = fmaf(cA, bf2f(a0.x), accA[0]);
        accA[1] = fmaf(cA, bf2f(a0.y), accA[1]);
        accA[2] = fmaf(cA, bf2f(a0.z), accA[2]);
        accA[3] = fmaf(cA, bf2f(a0.w), accA[3]);
        accA[4] = fmaf(cA, bf2f(a1.x), accA[4]);
        accA[5] = fmaf(cA, bf2f(a1.y), accA[5]);
        accA[6] = fmaf(cA, bf2f(a1.z), accA[6]);
        accA[7] = fmaf(cA, bf2f(a1.w), accA[7]);
        accB[0] = fmaf(cB, bf2f(b0.x), accB[0]);
        accB[1] = fmaf(cB, bf2f(b0.y), accB[1]);
        accB[2] = fmaf(cB, bf2f(b0.z), accB[2]);
        accB[3] = fmaf(cB, bf2f(b0.w), accB[3]);
        accB[4] = fmaf(cB, bf2f(b1.x), accB[4]);
        accB[5] = fmaf(cB, bf2f(b1.y), accB[5]);
        accB[6] = fmaf(cB, bf2f(b1.z), accB[6]);
        accB[7] = fmaf(cB, bf2f(b1.w), accB[7]);
    }
    float* ypA = y + (long long)row0 * DIM_ + lane * 8;
    float* ypB = ypA + DIM_;
    *(float4*)(ypA + 0) = make_float4(accA[0], accA[1], accA[2], accA[3]);
    *(float4*)(ypA + 4) = make_float4(accA[4], accA[5], accA[6], accA[7]);
    *(float4*)(ypB + 0) = make_float4(accB[0], accB[1], accB[2], accB[3]);
    *(float4*)(ypB + 4) = make_float4(accB[4], accB[5], accB[6], accB[7]);
}

extern "C" void kernel_launch(void* const* d_in, const int* in_sizes, int n_in,
                              void* d_out, int out_size, void* d_ws, size_t ws_size,
                              hipStream_t stream) {
    const float* x     = (const float*)d_in[0];
    const float* fc1_w = (const float*)d_in[1];
    const float* fc1_b = (const float*)d_in[2];
    const float* fc2_w = (const float*)d_in[3];
    const float* fc2_b = (const float*)d_in[4];
    const float* k1_w  = (const float*)d_in[5];
    const float* k1_b  = (const float*)d_in[6];
    const float* k2_w  = (const float*)d_in[7];
    const float* k2_b  = (const float*)d_in[8];
    const float* w1_w  = (const float*)d_in[9];
    const float* w1_b  = (const float*)d_in[10];
    const float* w2_w  = (const float*)d_in[11];
    const float* w2_b  = (const float*)d_in[12];

    char* ws = (char*)d_ws;
    short* h1b    = (short*)(ws + 0);              // 33,554,432 (live fc1->fc2)
    float* simbuf = (float*)(ws + 0);              // 33,554,432 (reuse after fc2)
    short* xb     = (short*)(ws + 33554432);       // 8,388,608
    short* hb     = (short*)(ws + 67108864);       // 8,388,608
    short* w1b    = (short*)(ws + 75497472);       // 2,097,152
    short* w2b    = (short*)(ws + 77594624);       // 2,097,152
    float* ppart  = (float*)(ws + 79691776);       // 524,288
    float* kcont  = (float*)(ws + 80216064);       // 128
    float* wbr    = (float*)(ws + 80216192);       // 128

    float* y = (float*)d_out;

    // 0) fused prep: pooled partials + x->bf16 (blocks 0..255), weights->bf16 (256..511)
    prep_kernel<<<dim3(512), dim3(512), 0, stream>>>(x, ppart, xb, fc1_w, fc2_w, w1b, w2b);
    // 1) pooled reduce + head nets
    pool_heads_kernel<<<dim3(B_), dim3(512), 0, stream>>>(ppart, k1_w, k1_b, k2_w, k2_b,
                                                          w1_w, w1_b, w2_w, w2_b, kcont, wbr);
    // 2) h1 = relu(x @ fc1_w^T + b1) -> bf16    M=8192 N=2048 K=512 (128x128, m-XCD swizzle)
    gemm_mfma<0, 128, 0><<<dim3(HID_ / 128, ROWS_ / 128, 1), dim3(256), 0, stream>>>(
        xb, w1b, fc1_b, nullptr, h1b, ROWS_, HID_, DIM_, DIM_, DIM_, 0, 0, 0);
    // 3) h = h1 @ fc2_w^T + b2 -> bf16 direct   M=8192 N=512 K=2048 (128x64, m-XCD swizzle)
    gemm_mfma<1, 64, 0><<<dim3(DIM_ / 64, ROWS_ / 128, 1), dim3(256), 0, stream>>>(
        h1b, w2b, fc2_b, nullptr, hb, ROWS_, DIM_, HID_, HID_, HID_, 0, 0, 0);
    // 4) sim[b] = hb[b] @ hb[b]^T -> fp32       M=N=1024 K=512, batch 8 (batch-XCD swizzle)
    gemm_mfma<2, 128, 1><<<dim3(N_ / 128, N_ / 128, B_), dim3(256), 0, stream>>>(
        hb, hb, nullptr, simbuf, nullptr, N_, N_, DIM_, DIM_, DIM_,
        (long long)N_ * DIM_, (long long)N_ * DIM_, (long long)N_ * N_);
    // 5) fused per-row top-16 + aggregate into output (2 rows/wave)
    topk_agg_kernel<<<dim3(ROWS_ / 8), dim3(256), 0, stream>>>(
        simbuf, kcont, wbr, (const unsigned short*)hb, y);
}

// Round 13
// 212.079 us; speedup vs baseline: 1.0822x; 1.0321x over previous
//
#include <hip/hip_runtime.h>
#include <math.h>

#define DIM_ 512
#define HID_ 2048
#define B_ 8
#define N_ 1024
#define ROWS_ 8192   // B_*N_
#define TOPK 16      // exact: gate at rank>=16 is <= e^-54 (k<12), contribution ~1e-20

typedef __attribute__((ext_vector_type(8))) short short8;
typedef __attribute__((ext_vector_type(16))) float float16v;

__device__ __forceinline__ float sigm(float x) { return 1.f / (1.f + __expf(-x)); }

__device__ __forceinline__ short f2bf(float f) {           // RNE fp32 -> bf16
    unsigned u = __float_as_uint(f);
    u += 0x7FFF + ((u >> 16) & 1);
    return (short)(u >> 16);
}

__device__ __forceinline__ float bf2f(unsigned short s) {
    return __uint_as_float((unsigned)s << 16);
}

__device__ __forceinline__ unsigned f2ord(float f) {       // monotone fp32 -> u32
    unsigned u = __float_as_uint(f);
    return (u & 0x80000000u) ? ~u : (u | 0x80000000u);
}

__device__ __forceinline__ void gload16(const short* g, short* l) {
    __builtin_amdgcn_global_load_lds(
        (const __attribute__((address_space(1))) void*)g,
        (__attribute__((address_space(3))) void*)l, 16, 0, 0);
}

// ---------------- fused prep: pooled partials + x->bf16  |  weights->bf16 ----------------
__global__ __launch_bounds__(512)
void prep_kernel(const float* __restrict__ x, float* __restrict__ part, short* __restrict__ xb,
                 const float* __restrict__ w1, const float* __restrict__ w2,
                 short* __restrict__ o1, short* __restrict__ o2) {
    const int bx = blockIdx.x;
    if (bx < 256) {
        const int b = bx >> 5, chunk = bx & 31;
        const int c = threadIdx.x;                     // 512
        const long long base = ((long long)b * N_ + chunk * 32) * DIM_ + c;
        const float* xp = x + base;
        short* xo = xb + base;
        float s = 0.f;
        for (int n = 0; n < 32; ++n) {
            const float v = xp[(long long)n * DIM_];
            s += v;
            xo[(long long)n * DIM_] = f2bf(v);
        }
        part[(long long)bx * DIM_ + c] = s;
    } else {
        const int n4 = HID_ * DIM_ / 4;                // 262144 float4 per matrix
        int i = (bx - 256) * 2048 + threadIdx.x;
#pragma unroll
        for (int t = 0; t < 4; ++t, i += 512) {
            const float* in = (i < n4) ? w1 : w2;
            short* out = (i < n4) ? o1 : o2;
            const int j = (i < n4) ? i : (i - n4);
            const float4 v = *(const float4*)(in + (long long)j * 4);
            short4 o;
            o.x = f2bf(v.x); o.y = f2bf(v.y); o.z = f2bf(v.z); o.w = f2bf(v.w);
            *(short4*)(out + (long long)j * 4) = o;
        }
    }
}

// ---------------- pooled reduce + head nets (fused): k_cont (B,3), w (B,3) ----------------
__global__ __launch_bounds__(512)
void pool_heads_kernel(const float* __restrict__ part,
                       const float* __restrict__ k1w, const float* __restrict__ k1b,
                       const float* __restrict__ k2w, const float* __restrict__ k2b,
                       const float* __restrict__ w1w, const float* __restrict__ w1b,
                       const float* __restrict__ w2w, const float* __restrict__ w2b,
                       float* __restrict__ kcont, float* __restrict__ wbr) {
    const int b = blockIdx.x;
    const int t = threadIdx.x;                     // 512
    __shared__ float sp[DIM_];
    __shared__ float kh[128], wh[128];
    __shared__ float wraw[4];
    float s = 0.f;
    for (int g = 0; g < 32; ++g) s += part[((long long)b * 32 + g) * DIM_ + t];
    sp[t] = s * (1.f / 1024.f);
    __syncthreads();
    if (t < 128) {
        float ak = k1b[t], aw = w1b[t];
        for (int k = 0; k < DIM_; ++k) {
            const float pv = sp[k];
            ak = fmaf(pv, k1w[t * DIM_ + k], ak);
            aw = fmaf(pv, w1w[t * DIM_ + k], aw);
        }
        kh[t] = fmaxf(ak, 0.f);
        wh[t] = fmaxf(aw, 0.f);
    }
    __syncthreads();
    if (t < 3) {
        float rk = k2b[t], rw = w2b[t];
        for (int k = 0; k < 128; ++k) {
            rk = fmaf(kh[k], k2w[t * 128 + k], rk);
            rw = fmaf(wh[k], w2w[t * 128 + k], rw);
        }
        kcont[b * 3 + t] = 1.f + 11.f * sigm(rk);
        wraw[t] = rw;
    }
    __syncthreads();
    if (t == 0) {
        const float m = fmaxf(wraw[0], fmaxf(wraw[1], wraw[2]));
        const float e0 = __expf(wraw[0] - m), e1 = __expf(wraw[1] - m), e2 = __expf(wraw[2] - m);
        const float inv = 1.f / (e0 + e1 + e2);
        wbr[b * 3 + 0] = e0 * inv;
        wbr[b * 3 + 1] = e1 * inv;
        wbr[b * 3 + 2] = e2 * inv;
    }
}

// ---------------- bf16 MFMA NT GEMM, 32x32x16, 128xBN tile, XCD-swizzled ----------------
// SWZ=1: batch = id % 8 -> each batch L2-resident on one XCD (sim).
// SWZ=2: batch-pinned m: mi = (id&7)*(numM/8) + (id>>3)%(numM/8), ni = id/numM
//        -> m-tiles of output-batch b produced on XCD b; A-tile n-reuse kept
//        (same-mi blocks differ by multiples of numM === 0 mod 8). numM%64==0.
// A/B frag: m|n = lane&31, k = (lane>>5)*8 + j.  C/D: col=lane&31,
// row=(reg&3)+8*(reg>>2)+4*(lane>>5)  [m74/m101-verified].
// OUTMODE: 0 = bf16 out, bias+relu; 1 = bf16 out, bias; 2 = fp32 raw (no bias)
template<int OUTMODE, int BN, int SWZ>
__global__ __launch_bounds__(256)
void gemm_mfma(const short* __restrict__ A, const short* __restrict__ Bm,
               const float* __restrict__ bias,
               float* __restrict__ outF, short* __restrict__ outB,
               int M, int N, int K, int lda, int ldb,
               long long sA, long long sB, long long sC) {
    constexpr int NJ = BN / 64;             // j-frags per wave (2 or 1)
    int bz, mi, ni;
    if (SWZ == 1) {
        const int id = blockIdx.x + gridDim.x * (blockIdx.y + gridDim.y * blockIdx.z);
        bz = id % gridDim.z;
        const int r = id / gridDim.z;
        ni = r % gridDim.x;
        mi = r / gridDim.x;
    } else {
        const int id = blockIdx.x + gridDim.x * blockIdx.y;
        const int numM = gridDim.y;
        const int mg = numM >> 3;           // m-tiles per batch-eighth
        bz = blockIdx.z;
        mi = (id & 7) * mg + (id >> 3) % mg;
        ni = id / numM;
    }
    A  += (long long)bz * sA;
    Bm += (long long)bz * sB;

    __shared__ short As[128 * 64];
    __shared__ short Bs[BN * 64];

    const int tid = threadIdx.x;
    const int lane = tid & 63;
    const int wv = tid >> 6;                // 0..3
    const int m0 = mi * 128;
    const int n0 = ni * BN;

    const int lrow = lane >> 3;             // 0..7
    const int cg = (lane & 7) ^ lrow;       // XOR swizzle

    const int ml = (wv & 1) * 64;
    const int nl = (wv >> 1) * (BN / 2);    // BN=128 -> 64, BN=64 -> 32
    const int fr = lane & 31;               // fragment row/col (m or n)
    const int khh = lane >> 5;              // k-half 0..1

    float16v acc[2][NJ];
#pragma unroll
    for (int i = 0; i < 2; ++i)
#pragma unroll
        for (int j = 0; j < NJ; ++j)
#pragma unroll
            for (int r = 0; r < 16; ++r) acc[i][j][r] = 0.f;

    for (int k0 = 0; k0 < K; k0 += 64) {
        __syncthreads();
#pragma unroll
        for (int i = 0; i < 4; ++i) {
            const int rloc = wv * 32 + i * 8 + lrow;
            gload16(A + (long long)(m0 + rloc) * lda + (k0 + cg * 8),
                    &As[(wv * 32 + i * 8) * 64]);
        }
#pragma unroll
        for (int i = 0; i < BN / 32; ++i) {
            const int rloc = wv * (BN / 4) + i * 8 + lrow;
            gload16(Bm + (long long)(n0 + rloc) * ldb + (k0 + cg * 8),
                    &Bs[(wv * (BN / 4) + i * 8) * 64]);
        }
        __syncthreads();
#pragma unroll
        for (int c = 0; c < 4; ++c) {           // 4 ksteps of K=16
            const int ch = c * 2 + khh;         // 8-elem chunk index
            short8 af[2], bfr[NJ];
#pragma unroll
            for (int i = 0; i < 2; ++i) {
                const int m = ml + i * 32 + fr;
                af[i] = *(const short8*)&As[m * 64 + ((ch ^ (m & 7)) * 8)];
            }
#pragma unroll
            for (int j = 0; j < NJ; ++j) {
                const int n = nl + j * 32 + fr;
                bfr[j] = *(const short8*)&Bs[n * 64 + ((ch ^ (n & 7)) * 8)];
            }
#pragma unroll
            for (int i = 0; i < 2; ++i)
#pragma unroll
                for (int j = 0; j < NJ; ++j)
                    acc[i][j] = __builtin_amdgcn_mfma_f32_32x32x16_bf16(
                        af[i], bfr[j], acc[i][j], 0, 0, 0);
        }
    }

    const long long outOfs = (long long)bz * sC;
#pragma unroll
    for (int i = 0; i < 2; ++i) {
#pragma unroll
        for (int j = 0; j < NJ; ++j) {
            const int ng = n0 + nl + j * 32 + fr;
            float bv = 0.f;
            if (OUTMODE != 2) bv = bias[ng];
#pragma unroll
            for (int r = 0; r < 16; ++r) {
                const int mg2 = m0 + ml + i * 32 + (r & 3) + 8 * (r >> 2) + 4 * khh;
                float v = acc[i][j][r] + bv;
                if (OUTMODE == 0) v = fmaxf(v, 0.f);
                const long long idx = outOfs + (long long)mg2 * N + ng;
                if (OUTMODE == 2) outF[idx] = v;
                else              outB[idx] = f2bf(v);
            }
        }
    }
}

// ---------------- fused per-row top-16 + aggregate, TWO rows per wave ----------------
// Block->row mapping batch-pinned: b = id&7 (same XCD as sim/hb batch b's L2).
__global__ __launch_bounds__(256)
void topk_agg_kernel(const float* __restrict__ sim,
                     const float* __restrict__ kcont, const float* __restrict__ wbr,
                     const unsigned short* __restrict__ h, float* __restrict__ y) {
    const int wv = threadIdx.x >> 6;
    const int lane = threadIdx.x & 63;
    const int ll = lane & 15;
    const int id = blockIdx.x;                    // 1024
    const int b = id & 7;                         // batch -> XCD pinned
    const int row0 = b * N_ + (id >> 3) * 8 + wv * 2;
    const float* srowA = sim + (long long)row0 * N_;
    const float* srowB = srowA + N_;

    const int base = lane * 16;
    float fA[16], fB[16];
#pragma unroll
    for (int q = 0; q < 4; ++q) {
        const float4 va = *(const float4*)(srowA + base + q * 4);
        const float4 vb = *(const float4*)(srowB + base + q * 4);
        fA[q * 4 + 0] = va.x; fA[q * 4 + 1] = va.y; fA[q * 4 + 2] = va.z; fA[q * 4 + 3] = va.w;
        fB[q * 4 + 0] = vb.x; fB[q * 4 + 1] = vb.y; fB[q * 4 + 2] = vb.z; fB[q * 4 + 3] = vb.w;
    }

    // row max (both rows, interleaved)
    float mA = fA[0], mB = fB[0];
#pragma unroll
    for (int j = 1; j < 16; ++j) { mA = fmaxf(mA, fA[j]); mB = fmaxf(mB, fB[j]); }
#pragma unroll
    for (int d = 32; d > 0; d >>= 1) {
        mA = fmaxf(mA, __shfl_xor(mA, d));
        mB = fmaxf(mB, __shfl_xor(mB, d));
    }
    const float maxvA = mA, maxvB = mB;

    // softmax denominators
    float sAo = 0.f, sBo = 0.f;
#pragma unroll
    for (int j = 0; j < 16; ++j) { sAo += __expf(fA[j] - maxvA); sBo += __expf(fB[j] - maxvB); }
#pragma unroll
    for (int d = 32; d > 0; d >>= 1) {
        sAo += __shfl_xor(sAo, d);
        sBo += __shfl_xor(sBo, d);
    }
    const float invdenA = 1.f / sAo, invdenB = 1.f / sBo;

    // ---- Phase A: u32 keys, both rows ----
    unsigned keyA[16], keyB[16];
#pragma unroll
    for (int j = 0; j < 16; ++j) {
        keyA[j] = (f2ord(fA[j]) & 0xFFFFFC00u) | (unsigned)(1023 - (base + j));
        keyB[j] = (f2ord(fB[j]) & 0xFFFFFC00u) | (unsigned)(1023 - (base + j));
    }

    // lane-local bitonic sort, descending (interleaved)
#pragma unroll
    for (int k = 2; k <= 16; k <<= 1) {
#pragma unroll
        for (int j = k >> 1; j > 0; j >>= 1) {
#pragma unroll
            for (int i = 0; i < 16; ++i) {
                const int l = i ^ j;
                if (l > i) {
                    const bool desc = ((i & k) == 0);
                    {
                        const unsigned a = keyA[i], bk = keyA[l];
                        const unsigned hi = (a > bk) ? a : bk;
                        const unsigned lo = (a > bk) ? bk : a;
                        keyA[i] = desc ? hi : lo;
                        keyA[l] = desc ? lo : hi;
                    }
                    {
                        const unsigned a = keyB[i], bk = keyB[l];
                        const unsigned hi = (a > bk) ? a : bk;
                        const unsigned lo = (a > bk) ? bk : a;
                        keyB[i] = desc ? hi : lo;
                        keyB[l] = desc ? lo : hi;
                    }
                }
            }
        }
    }

    // 6 merge rounds (interleaved)
#pragma unroll
    for (int d = 1; d < 64; d <<= 1) {
        unsigned oA[16], oB[16];
#pragma unroll
        for (int i = 0; i < 16; ++i) {
            oA[i] = __shfl_xor(keyA[15 - i], d);
            oB[i] = __shfl_xor(keyB[15 - i], d);
        }
#pragma unroll
        for (int i = 0; i < 16; ++i) {
            keyA[i] = (keyA[i] > oA[i]) ? keyA[i] : oA[i];
            keyB[i] = (keyB[i] > oB[i]) ? keyB[i] : oB[i];
        }
#pragma unroll
        for (int j = 8; j > 0; j >>= 1) {
#pragma unroll
            for (int i = 0; i < 16; ++i) {
                if ((i & j) == 0) {
                    {
                        const unsigned a = keyA[i], bk = keyA[i | j];
                        keyA[i]     = (a > bk) ? a : bk;
                        keyA[i | j] = (a > bk) ? bk : a;
                    }
                    {
                        const unsigned a = keyB[i], bk = keyB[i | j];
                        keyB[i]     = (a > bk) ? a : bk;
                        keyB[i | j] = (a > bk) ? bk : a;
                    }
                }
            }
        }
    }

    // ---- Phase B: groups {0,2} -> row A, {1,3} -> row B ----
    const int rowSel = (lane >> 4) & 1;
    unsigned k32 = 0;
#pragma unroll
    for (int j = 0; j < 16; ++j) {
        const unsigned sel = rowSel ? keyB[j] : keyA[j];
        k32 = (ll == j) ? sel : k32;
    }
    const int myidx = 1023 - (int)(k32 & 1023u);
    const float* srow = rowSel ? srowB : srowA;
    const float myval = srow[myidx];                 // L1/L2-hot exact fp32

    unsigned long long kx = ((unsigned long long)f2ord(myval) << 32)
                          | (unsigned)(1023 - myidx);
#pragma unroll
    for (int k = 2; k <= 16; k <<= 1) {
#pragma unroll
        for (int d = k >> 1; d > 0; d >>= 1) {
            const unsigned long long other = __shfl_xor(kx, d);
            const bool keepMax = (((ll & k) != 0) == ((ll & d) != 0));
            const bool mineBig = (kx > other);
            kx = (keepMax == mineBig) ? kx : other;
        }
    }
    const unsigned sord = (unsigned)(kx >> 32);
    const unsigned su = (sord & 0x80000000u) ? (sord & 0x7FFFFFFFu) : ~sord;
    const float sval = __uint_as_float(su);
    const int sidx = 1023 - (int)(kx & 1023u);

    const float kc0 = kcont[b * 3 + 0], kc1 = kcont[b * 3 + 1], kc2 = kcont[b * 3 + 2];
    const float w0 = wbr[b * 3 + 0], w1 = wbr[b * 3 + 1], w2 = wbr[b * 3 + 2];

    const float mv = rowSel ? maxvB : maxvA;
    const float ivd = rowSel ? invdenB : invdenA;
    const float p = __expf(sval - mv) * ivd;
    const float rr = (float)ll + 0.5f;
    const float g0 = sigm(12.f * (kc0 - rr));
    const float g1 = sigm(12.f * (kc1 - rr));
    const float g2 = sigm(12.f * (kc2 - rr));
    float s0 = p * g0, s1 = p * g1, s2 = p * g2;
#pragma unroll
    for (int d = 1; d < 16; d <<= 1) {
        s0 += __shfl_xor(s0, d);
        s1 += __shfl_xor(s1, d);
        s2 += __shfl_xor(s2, d);
    }
    const float f0 = w0 / (s0 + 1e-8f);
    const float f1 = w1 / (s1 + 1e-8f);
    const float f2 = w2 / (s2 + 1e-8f);
    const float mycoef = p * (f0 * g0 + f1 * g1 + f2 * g2);

    // gather both rows: row A coefs in groups 0,2; row B in groups 1,3
    const unsigned short* hbase = h + (long long)b * (N_ * DIM_) + lane * 8;
    float accA[8] = {0.f, 0.f, 0.f, 0.f, 0.f, 0.f, 0.f, 0.f};
    float accB[8] = {0.f, 0.f, 0.f, 0.f, 0.f, 0.f, 0.f, 0.f};
    const int half = lane & 32;
#pragma unroll
    for (int r = 0; r < 16; ++r) {
        const float cA = __shfl(mycoef, half | r);
        const int   iA = __shfl(sidx,  half | r);
        const float cB = __shfl(mycoef, half | 16 | r);
        const int   iB = __shfl(sidx,  half | 16 | r);
        const ushort4 a0 = *(const ushort4*)(hbase + (long long)iA * DIM_);
        const ushort4 a1 = *(const ushort4*)(hbase + (long long)iA * DIM_ + 4);
        const ushort4 b0 = *(const ushort4*)(hbase + (long long)iB * DIM_);
        const ushort4 b1 = *(const ushort4*)(hbase + (long long)iB * DIM_ + 4);
        accA[0] = fmaf(cA, bf2f(a0.x), accA[0]);
        accA[1] = fmaf(cA, bf2f(a0.y), accA[1]);
        accA[2] = fmaf(cA, bf2f(a0.z), accA[2]);
        accA[3] = fmaf(cA, bf2f(a0.w), accA[3]);
        accA[4] = fmaf(cA, bf2f(a1.x), accA[4]);
        accA[5] = fmaf(cA, bf2f(a1.y), accA[5]);
        accA[6] = fmaf(cA, bf2f(a1.z), accA[6]);
        accA[7] = fmaf(cA, bf2f(a1.w), accA[7]);
        accB[0] = fmaf(cB, bf2f(b0.x), accB[0]);
        accB[1] = fmaf(cB, bf2f(b0.y), accB[1]);
        accB[2] = fmaf(cB, bf2f(b0.z), accB[2]);
        accB[3] = fmaf(cB, bf2f(b0.w), accB[3]);
        accB[4] = fmaf(cB, bf2f(b1.x), accB[4]);
        accB[5] = fmaf(cB, bf2f(b1.y), accB[5]);
        accB[6] = fmaf(cB, bf2f(b1.z), accB[6]);
        accB[7] = fmaf(cB, bf2f(b1.w), accB[7]);
    }
    float* ypA = y + (long long)row0 * DIM_ + lane * 8;
    float* ypB = ypA + DIM_;
    *(float4*)(ypA + 0) = make_float4(accA[0], accA[1], accA[2], accA[3]);
    *(float4*)(ypA + 4) = make_float4(accA[4], accA[5], accA[6], accA[7]);
    *(float4*)(ypB + 0) = make_float4(accB[0], accB[1], accB[2], accB[3]);
    *(float4*)(ypB + 4) = make_float4(accB[4], accB[5], accB[6], accB[7]);
}

extern "C" void kernel_launch(void* const* d_in, const int* in_sizes, int n_in,
                              void* d_out, int out_size, void* d_ws, size_t ws_size,
                              hipStream_t stream) {
    const float* x     = (const float*)d_in[0];
    const float* fc1_w = (const float*)d_in[1];
    const float* fc1_b = (const float*)d_in[2];
    const float* fc2_w = (const float*)d_in[3];
    const float* fc2_b = (const float*)d_in[4];
    const float* k1_w  = (const float*)d_in[5];
    const float* k1_b  = (const float*)d_in[6];
    const float* k2_w  = (const float*)d_in[7];
    const float* k2_b  = (const float*)d_in[8];
    const float* w1_w  = (const float*)d_in[9];
    const float* w1_b  = (const float*)d_in[10];
    const float* w2_w  = (const float*)d_in[11];
    const float* w2_b  = (const float*)d_in[12];

    char* ws = (char*)d_ws;
    short* h1b    = (short*)(ws + 0);              // 33,554,432 (live fc1->fc2)
    float* simbuf = (float*)(ws + 0);              // 33,554,432 (reuse after fc2)
    short* xb     = (short*)(ws + 33554432);       // 8,388,608
    short* hb     = (short*)(ws + 67108864);       // 8,388,608
    short* w1b    = (short*)(ws + 75497472);       // 2,097,152
    short* w2b    = (short*)(ws + 77594624);       // 2,097,152
    float* ppart  = (float*)(ws + 79691776);       // 524,288
    float* kcont  = (float*)(ws + 80216064);       // 128
    float* wbr    = (float*)(ws + 80216192);       // 128

    float* y = (float*)d_out;

    // 0) fused prep: pooled partials + x->bf16 (blocks 0..255), weights->bf16 (256..511)
    prep_kernel<<<dim3(512), dim3(512), 0, stream>>>(x, ppart, xb, fc1_w, fc2_w, w1b, w2b);
    // 1) pooled reduce + head nets
    pool_heads_kernel<<<dim3(B_), dim3(512), 0, stream>>>(ppart, k1_w, k1_b, k2_w, k2_b,
                                                          w1_w, w1_b, w2_w, w2_b, kcont, wbr);
    // 2) h1 = relu(x @ fc1_w^T + b1) -> bf16    M=8192 N=2048 K=512 (128x128, batch-pinned m)
    gemm_mfma<0, 128, 2><<<dim3(HID_ / 128, ROWS_ / 128, 1), dim3(256), 0, stream>>>(
        xb, w1b, fc1_b, nullptr, h1b, ROWS_, HID_, DIM_, DIM_, DIM_, 0, 0, 0);
    // 3) h = h1 @ fc2_w^T + b2 -> bf16 direct   M=8192 N=512 K=2048 (128x64, batch-pinned m)
    gemm_mfma<1, 64, 2><<<dim3(DIM_ / 64, ROWS_ / 128, 1), dim3(256), 0, stream>>>(
        h1b, w2b, fc2_b, nullptr, hb, ROWS_, DIM_, HID_, HID_, HID_, 0, 0, 0);
    // 4) sim[b] = hb[b] @ hb[b]^T -> fp32       M=N=1024 K=512, batch 8 (batch-XCD pinned)
    gemm_mfma<2, 128, 1><<<dim3(N_ / 128, N_ / 128, B_), dim3(256), 0, stream>>>(
        hb, hb, nullptr, simbuf, nullptr, N_, N_, DIM_, DIM_, DIM_,
        (long long)N_ * DIM_, (long long)N_ * DIM_, (long long)N_ * N_);
    // 5) fused per-row top-16 + aggregate into output (2 rows/wave, batch-pinned blocks)
    topk_agg_kernel<<<dim3(ROWS_ / 8), dim3(256), 0, stream>>>(
        simbuf, kcont, wbr, (const unsigned short*)hb, y);
}